// Round 2
// baseline (5230.430 us; speedup 1.0000x reference)
//
#include <hip/hip_runtime.h>
#include <stdint.h>

#define T_SZ 128
#define B_SZ 32
#define D_SZ 1024
#define L_SZ 2
#define V_SZ 50257
#define TB   4096
#define DEC_SZ 205852672ull  // TB * V

typedef __attribute__((ext_vector_type(8))) short          short8;
typedef __attribute__((ext_vector_type(8))) unsigned short ushort8;
typedef __attribute__((ext_vector_type(4))) unsigned short ushort4v;
typedef __attribute__((ext_vector_type(4))) float          f32x4;

__device__ __forceinline__ float bf2f(unsigned short u) {
  union { unsigned int i; float f; } v; v.i = ((unsigned int)u) << 16; return v.f;
}
__device__ __forceinline__ unsigned short f2bf(float f) {
  union { float f; unsigned int i; } v; v.f = f;
  unsigned int r = v.i + 0x7fffu + ((v.i >> 16) & 1u);  // RNE
  return (unsigned short)(r >> 16);
}
__device__ __forceinline__ void split_bf(float f, unsigned short& hi, unsigned short& lo) {
  hi = f2bf(f);
  lo = f2bf(f - bf2f(hi));
}
__device__ __forceinline__ f32x4 mfma16(short8 a, short8 b, f32x4 c) {
  return __builtin_amdgcn_mfma_f32_16x16x32_bf16(a, b, c, 0, 0, 0);
}
__device__ __forceinline__ void gload16(const void* g, void* l) {
  __builtin_amdgcn_global_load_lds((const __attribute__((address_space(1))) void*)g,
                                   (__attribute__((address_space(3))) void*)l, 16, 0, 0);
}

// ---------------------------------------------------------------------------
// prep_w: transpose + bf16-split Wi/Wh.
// In : W[lk][dk][g] fp32 (lk = l*2+blk, dk<512, g<2048)
// Out: Wt*[lk][g][dk] bf16 hi/lo (row = gate-row, 512 contiguous k)
// grid 4096 = lk(4) * gt(64) * dt(16), block (32,8)
// ---------------------------------------------------------------------------
__global__ void prep_w(const float* __restrict__ Wi, const float* __restrict__ Wh,
                       unsigned short* __restrict__ Withi, unsigned short* __restrict__ Witlo,
                       unsigned short* __restrict__ Whthi, unsigned short* __restrict__ Whtlo) {
  __shared__ float tile[32][33];
  int bid = blockIdx.x;
  int lk = bid >> 10;
  int gt = (bid & 1023) >> 4;
  int dt = bid & 15;
  int tx = threadIdx.x, ty = threadIdx.y;
  for (int pass = 0; pass < 2; ++pass) {
    const float* W = pass ? Wh : Wi;
    unsigned short* Ohi = pass ? Whthi : Withi;
    unsigned short* Olo = pass ? Whtlo : Witlo;
    if (pass) __syncthreads();
#pragma unroll
    for (int i = 0; i < 4; ++i) {
      int dk = dt * 32 + ty + i * 8;
      tile[ty + i * 8][tx] = W[((size_t)lk * 512 + dk) * 2048 + gt * 32 + tx];
    }
    __syncthreads();
#pragma unroll
    for (int i = 0; i < 4; ++i) {
      int g  = gt * 32 + ty + i * 8;
      int dk = dt * 32 + tx;
      float v = tile[tx][ty + i * 8];
      unsigned short hi, lo; split_bf(v, hi, lo);
      size_t oidx = ((size_t)lk * 2048 + g) * 512 + dk;
      Ohi[oidx] = hi; Olo[oidx] = lo;
    }
  }
}

// ---------------------------------------------------------------------------
// prep_embed: x0 = split(emb[tokens]); grid 4096 x 256, 4 elems/thread
// ---------------------------------------------------------------------------
__global__ void prep_embed(const int* __restrict__ tokens, const float* __restrict__ emb,
                           unsigned short* __restrict__ xhi, unsigned short* __restrict__ xlo) {
  int idx = blockIdx.x * 256 + threadIdx.x;   // 0..1048575
  int r  = idx >> 8;
  int d4 = (idx & 255) * 4;
  int tok = tokens[r];
  f32x4 v = *(const f32x4*)(emb + (size_t)tok * 1024 + d4);
  ushort4v h, l;
#pragma unroll
  for (int q = 0; q < 4; ++q) {
    unsigned short hh, ll; split_bf(v[q], hh, ll);
    h[q] = hh; l[q] = ll;
  }
  size_t o = (size_t)r * 1024 + d4;
  *(ushort4v*)(xhi + o) = h;
  *(ushort4v*)(xlo + o) = l;
}

// ---------------------------------------------------------------------------
// prep_state2: init both layers' h/c state + bf16 h buffers (buf 0).
// grid 256 x 256 -> 65536 = L*B*D
// ---------------------------------------------------------------------------
__global__ void prep_state2(const float* __restrict__ h0, const float* __restrict__ c0,
                            float* __restrict__ h_f32, float* __restrict__ c_f32,
                            unsigned short* __restrict__ hb) {
  int idx = blockIdx.x * 256 + threadIdx.x;   // 0..65535
  int layer = idx >> 15;
  int i = idx & 32767;
  float h = h0[idx];
  float c = c0[idx];
  h_f32[idx] = h; c_f32[idx] = c;
  unsigned short hi, lo; split_bf(h, hi, lo);
  hb[((size_t)(layer * 2 + 0) * 2 + 0) * 32768 + i] = hi;
  hb[((size_t)(layer * 2 + 1) * 2 + 0) * 32768 + i] = lo;
}

// ---------------------------------------------------------------------------
// xg_kernel (layer 0 only): xg[r][n] = sum_k x[r][chunk*512+k]*Wit[chunk][n'][k] + b[n]
// M=4096, N=4096 (block-diag, chunk = n>>11), K=512, 3-pass bf16 split MFMA.
// grid 1024 (m-fast: 32 m x 32 n), 256 threads, 128x128 tile, BK=64.
// ---------------------------------------------------------------------------
__launch_bounds__(256, 2)
__global__ void xg_kernel(const unsigned short* __restrict__ xhi, const unsigned short* __restrict__ xlo,
                          const unsigned short* __restrict__ Withi, const unsigned short* __restrict__ Witlo,
                          const float* __restrict__ bias, float* __restrict__ xg) {
  __shared__ unsigned short lds[32768];  // 64KB: Ahi|Alo|Bhi|Blo 16KB each
  char* ldsb = (char*)lds;
  const int tid = threadIdx.x;
  const int lane = tid & 63;
  const int w = tid >> 6;
  const int m0 = (blockIdx.x & 31) << 7;
  const int n0 = (blockIdx.x >> 5) << 7;
  const int wm = w >> 1, wn = w & 1;
  const int col = lane & 15, kg = lane >> 4;
  const int chunk = n0 >> 11;
  const int rl0 = n0 & 2047;
  // block-diagonal: chunk c consumes input dims [c*512, (c+1)*512)
  const char* Abase_h = (const char*)xhi + (size_t)m0 * 2048 + (size_t)chunk * 1024;
  const char* Abase_l = (const char*)xlo + (size_t)m0 * 2048 + (size_t)chunk * 1024;
  const char* Bbase_h = (const char*)Withi + ((size_t)chunk * 2048 + rl0) * 1024;
  const char* Bbase_l = (const char*)Witlo + ((size_t)chunk * 2048 + rl0) * 1024;
  f32x4 acc[4][4] = {};
  for (int ks = 0; ks < 8; ++ks) {
    if (ks) __syncthreads();
#pragma unroll
    for (int i = 0; i < 4; ++i) {
      int o = tid * 16 + i * 4096;
      int r = o >> 7, cb = o & 127;
      int sc = cb ^ ((r & 7) << 4);          // pre-swizzled source (rule #21)
      int wdst = w * 1024 + i * 4096;        // wave-uniform LDS base
      gload16(Abase_h + (size_t)r * 2048 + ks * 128 + sc, ldsb + wdst);
      gload16(Abase_l + (size_t)r * 2048 + ks * 128 + sc, ldsb + 16384 + wdst);
      gload16(Bbase_h + (size_t)r * 1024 + ks * 128 + sc, ldsb + 32768 + wdst);
      gload16(Bbase_l + (size_t)r * 1024 + ks * 128 + sc, ldsb + 49152 + wdst);
    }
    __syncthreads();
#pragma unroll
    for (int kh = 0; kh < 2; ++kh) {
      short8 ah[4], al[4], bh[4], bl[4];
#pragma unroll
      for (int i = 0; i < 4; ++i) {
        int ra = wm * 64 + i * 16 + col;
        int kb = kh * 64 + kg * 16;
        int aad = ra * 128 + (kb ^ ((ra & 7) << 4));
        ah[i] = *(const short8*)(ldsb + aad);
        al[i] = *(const short8*)(ldsb + 16384 + aad);
        int rb = wn * 64 + i * 16 + col;
        int bad = rb * 128 + (kb ^ ((rb & 7) << 4));
        bh[i] = *(const short8*)(ldsb + 32768 + bad);
        bl[i] = *(const short8*)(ldsb + 49152 + bad);
      }
#pragma unroll
      for (int mi = 0; mi < 4; ++mi)
#pragma unroll
        for (int ni = 0; ni < 4; ++ni) {
          acc[mi][ni] = mfma16(ah[mi], bh[ni], acc[mi][ni]);
          acc[mi][ni] = mfma16(al[mi], bh[ni], acc[mi][ni]);
          acc[mi][ni] = mfma16(ah[mi], bl[ni], acc[mi][ni]);
        }
    }
  }
#pragma unroll
  for (int mi = 0; mi < 4; ++mi) {
    int rowb = m0 + wm * 64 + mi * 16 + (lane >> 4) * 4;
#pragma unroll
    for (int ni = 0; ni < 4; ++ni) {
      int cidx = n0 + wn * 64 + ni * 16 + col;
      float bb = bias[cidx];
#pragma unroll
      for (int r = 0; r < 4; ++r)
        xg[(size_t)(rowb + r) * 4096 + cidx] = acc[mi][ni][r] + bb;
    }
  }
}

// ---------------------------------------------------------------------------
// lstm_step2: pipelined two-layer step. Phase p runs layer0@t=p (WGs 0..127)
// and layer1@t=p-1 (WGs 128..255) -- no intra-launch dependency (layer1@t
// consumes layer0@t written in the PREVIOUS launch).
// layer0 gates = xg0[t] + h.Wh0;  layer1 gates = x1[t].Wi1 + h.Wh1 + b1.
// Per WG: 8 hidden units x all 4 gates; 4 waves; 16x16x32 MFMA, 3-pass split.
// ---------------------------------------------------------------------------
__global__ void lstm_step2(unsigned short* __restrict__ hb,   // [layer][hilo][buf][32768]
                           unsigned short* __restrict__ x1hi, unsigned short* __restrict__ x1lo,
                           unsigned short* __restrict__ x0hi, unsigned short* __restrict__ x0lo,
                           const unsigned short* __restrict__ Withi, const unsigned short* __restrict__ Witlo,
                           const unsigned short* __restrict__ Whthi, const unsigned short* __restrict__ Whtlo,
                           const float* __restrict__ xg0, const float* __restrict__ bias,
                           float* __restrict__ h_f32, float* __restrict__ c_f32,  // [layer][32768]
                           int p) {
  const int layer = blockIdx.x >> 7;
  const int t = layer ? p - 1 : p;
  if (t < 0 || t >= T_SZ) return;
  const int d0 = (blockIdx.x & 127) * 8;
  const int tid = threadIdx.x;
  const int lane = tid & 63;
  const int w = tid >> 6;
  const int mf = w & 1, fr = w >> 1;
  const int c = lane & 15, kg = lane >> 4;
  const int grp_in = c >> 3, dl = c & 7;
  const int rl = grp_in * 1024 + d0 + dl;   // gate-row within chunk fr
  const int arow = mf * 16 + c;             // batch index for A-frag

  const unsigned short* hin_hi = hb + ((size_t)(layer * 2 + 0) * 2 + (t & 1)) * 32768;
  const unsigned short* hin_lo = hb + ((size_t)(layer * 2 + 1) * 2 + (t & 1)) * 32768;
  unsigned short* hout_hi = hb + ((size_t)(layer * 2 + 0) * 2 + ((t + 1) & 1)) * 32768;
  unsigned short* hout_lo = hb + ((size_t)(layer * 2 + 1) * 2 + ((t + 1) & 1)) * 32768;
  unsigned short* xo_hi = layer ? x0hi : x1hi;
  unsigned short* xo_lo = layer ? x0lo : x1lo;

  const unsigned short* Bh = Whthi + ((size_t)(layer * 2 + fr) * 2048 + rl) * 512;
  const unsigned short* Bl = Whtlo + ((size_t)(layer * 2 + fr) * 2048 + rl) * 512;
  const unsigned short* Ah = hin_hi + (size_t)arow * 1024 + fr * 512;
  const unsigned short* Al = hin_lo + (size_t)arow * 1024 + fr * 512;

  f32x4 ac0 = {}, ac1 = {}, ac2 = {};   // 3 independent MFMA chains
#pragma unroll 4
  for (int ks = 0; ks < 16; ++ks) {
    int ko = ks * 32 + kg * 8;
    short8 a_h = *(const short8*)(Ah + ko);
    short8 a_l = *(const short8*)(Al + ko);
    short8 b_h = *(const short8*)(Bh + ko);
    short8 b_l = *(const short8*)(Bl + ko);
    ac0 = mfma16(a_h, b_h, ac0);
    ac1 = mfma16(a_l, b_h, ac1);
    ac2 = mfma16(a_h, b_l, ac2);
  }
  if (layer) {  // + x1[t] . Wi1 (couldn't be batched: x1 is produced phase-by-phase)
    const unsigned short* BWh = Withi + ((size_t)(2 + fr) * 2048 + rl) * 512;
    const unsigned short* BWl = Witlo + ((size_t)(2 + fr) * 2048 + rl) * 512;
    const unsigned short* Axh = x1hi + (size_t)(t * 32 + arow) * 1024 + fr * 512;
    const unsigned short* Axl = x1lo + (size_t)(t * 32 + arow) * 1024 + fr * 512;
#pragma unroll 4
    for (int ks = 0; ks < 16; ++ks) {
      int ko = ks * 32 + kg * 8;
      short8 a_h = *(const short8*)(Axh + ko);
      short8 a_l = *(const short8*)(Axl + ko);
      short8 b_h = *(const short8*)(BWh + ko);
      short8 b_l = *(const short8*)(BWl + ko);
      ac0 = mfma16(a_h, b_h, ac0);
      ac1 = mfma16(a_l, b_h, ac1);
      ac2 = mfma16(a_h, b_l, ac2);
    }
  }
  __shared__ float gl[1024];  // [grp][b][dl]
  const int grp = fr * 2 + grp_in;
#pragma unroll
  for (int r = 0; r < 4; ++r) {
    int bb = mf * 16 + (lane >> 4) * 4 + r;   // C layout: row=(lane>>4)*4+reg
    float g = ac0[r] + ac1[r] + ac2[r];
    if (!layer) g += xg0[(size_t)(t * 32 + bb) * 4096 + grp * 1024 + d0 + dl];
    gl[grp * 256 + bb * 8 + dl] = g;
  }
  __syncthreads();
  // elementwise: 256 threads = 32 b x 8 dl
  int b2 = tid >> 3, dl2 = tid & 7, d = d0 + dl2;
  float iv = gl[0 * 256 + b2 * 8 + dl2];
  float fv = gl[1 * 256 + b2 * 8 + dl2];
  float gv = gl[2 * 256 + b2 * 8 + dl2];
  float ov = gl[3 * 256 + b2 * 8 + dl2];
  if (layer) {
    iv += bias[4096 + 0 * 1024 + d];
    fv += bias[4096 + 1 * 1024 + d];
    gv += bias[4096 + 2 * 1024 + d];
    ov += bias[4096 + 3 * 1024 + d];
  }
  size_t so = (size_t)layer * 32768 + b2 * 1024 + d;
  float co = c_f32[so];
  float sf = 1.f / (1.f + expf(-fv));
  float si = 1.f / (1.f + expf(-iv));
  float sg = 1.f / (1.f + expf(-ov));
  float cn = sf * co + si * tanhf(gv);
  float hn = sg * tanhf(cn);
  c_f32[so] = cn;
  h_f32[so] = hn;
  unsigned short hh, hl; split_bf(hn, hh, hl);
  hout_hi[b2 * 1024 + d] = hh;
  hout_lo[b2 * 1024 + d] = hl;
  size_t xo = (size_t)(t * 32 + b2) * 1024 + d;
  xo_hi[xo] = hh;
  xo_lo[xo] = hl;
}

// ---------------------------------------------------------------------------
// save_states2: final h/c of both layers -> d_out tail + the 0.0 scalar.
// ---------------------------------------------------------------------------
__global__ void save_states2(const float* __restrict__ h_f32, const float* __restrict__ c_f32,
                             float* __restrict__ out) {
  int idx = blockIdx.x * 256 + threadIdx.x;   // 0..65535 = (L,B,D) flat
  out[DEC_SZ + idx] = h_f32[idx];
  out[DEC_SZ + 65536 + idx] = c_f32[idx];
  if (idx == 0) out[DEC_SZ + 131072] = 0.0f;
}

// ---------------------------------------------------------------------------
// dec_kernel: decoded = hs . Wdec^T + bdec. M=4096, N=50257(pad 50304), K=1024.
// A pre-split bf16 (global_load_lds), B fp32 split in-kernel (reg-staged).
// grid 12576 (m-fast: 32 m x 393 n), 128x128 tile, BK=64, 3-pass.
// ---------------------------------------------------------------------------
__launch_bounds__(256, 2)
__global__ void dec_kernel(const unsigned short* __restrict__ xhi, const unsigned short* __restrict__ xlo,
                           const float* __restrict__ Wdec, const float* __restrict__ bdec,
                           float* __restrict__ out) {
  __shared__ unsigned short lds[32768];
  char* ldsb = (char*)lds;
  const int tid = threadIdx.x;
  const int lane = tid & 63;
  const int w = tid >> 6;
  const int m0 = (blockIdx.x & 31) << 7;
  const int n0 = (blockIdx.x >> 5) << 7;
  const int wm = w >> 1, wn = w & 1;
  const int col = lane & 15, kg = lane >> 4;
  const char* Abase_h = (const char*)xhi + (size_t)m0 * 2048;
  const char* Abase_l = (const char*)xlo + (size_t)m0 * 2048;
  const int rv = tid >> 1, kh2 = tid & 1;
  int vrow = n0 + rv; if (vrow > V_SZ - 1) vrow = V_SZ - 1;
  const float* Bsrc = Wdec + (size_t)vrow * 1024 + kh2 * 32;
  f32x4 acc[4][4] = {};
  for (int ks = 0; ks < 16; ++ks) {
    if (ks) __syncthreads();
#pragma unroll
    for (int i = 0; i < 4; ++i) {
      int o = tid * 16 + i * 4096;
      int r = o >> 7, cb = o & 127;
      int sc = cb ^ ((r & 7) << 4);
      int wdst = w * 1024 + i * 4096;
      gload16(Abase_h + (size_t)r * 2048 + ks * 128 + sc, ldsb + wdst);
      gload16(Abase_l + (size_t)r * 2048 + ks * 128 + sc, ldsb + 16384 + wdst);
    }
#pragma unroll
    for (int j2 = 0; j2 < 4; ++j2) {
      f32x4 u  = *(const f32x4*)(Bsrc + ks * 64 + j2 * 8);
      f32x4 vv = *(const f32x4*)(Bsrc + ks * 64 + j2 * 8 + 4);
      ushort8 h8, l8;
#pragma unroll
      for (int q = 0; q < 4; ++q) {
        unsigned short hh, ll;
        split_bf(u[q], hh, ll);  h8[q] = hh;     l8[q] = ll;
        split_bf(vv[q], hh, ll); h8[4 + q] = hh; l8[4 + q] = ll;
      }
      int kb = kh2 * 64 + j2 * 16;
      int ad = rv * 128 + (kb ^ ((rv & 7) << 4));
      *(ushort8*)(ldsb + 32768 + ad) = h8;
      *(ushort8*)(ldsb + 49152 + ad) = l8;
    }
    __syncthreads();
#pragma unroll
    for (int kh = 0; kh < 2; ++kh) {
      short8 ah[4], al[4], bh[4], bl[4];
#pragma unroll
      for (int i = 0; i < 4; ++i) {
        int ra = wm * 64 + i * 16 + col;
        int kb = kh * 64 + kg * 16;
        int aad = ra * 128 + (kb ^ ((ra & 7) << 4));
        ah[i] = *(const short8*)(ldsb + aad);
        al[i] = *(const short8*)(ldsb + 16384 + aad);
        int rb = wn * 64 + i * 16 + col;
        int bad = rb * 128 + (kb ^ ((rb & 7) << 4));
        bh[i] = *(const short8*)(ldsb + 32768 + bad);
        bl[i] = *(const short8*)(ldsb + 49152 + bad);
      }
#pragma unroll
      for (int mi = 0; mi < 4; ++mi)
#pragma unroll
        for (int ni = 0; ni < 4; ++ni) {
          acc[mi][ni] = mfma16(ah[mi], bh[ni], acc[mi][ni]);
          acc[mi][ni] = mfma16(al[mi], bh[ni], acc[mi][ni]);
          acc[mi][ni] = mfma16(ah[mi], bl[ni], acc[mi][ni]);
        }
    }
  }
#pragma unroll
  for (int mi = 0; mi < 4; ++mi) {
    int rowb = m0 + wm * 64 + mi * 16 + (lane >> 4) * 4;
#pragma unroll
    for (int ni = 0; ni < 4; ++ni) {
      int v = n0 + wn * 64 + ni * 16 + col;
      if (v < V_SZ) {
        float bb = bdec[v];
#pragma unroll
        for (int r = 0; r < 4; ++r)
          out[(size_t)(rowb + r) * V_SZ + v] = acc[mi][ni][r] + bb;
      }
    }
  }
}

// ---------------------------------------------------------------------------
extern "C" void kernel_launch(void* const* d_in, const int* in_sizes, int n_in,
                              void* d_out, int out_size, void* d_ws, size_t ws_size,
                              hipStream_t stream) {
  const int*   tokens = (const int*)  d_in[0];
  const float* h0     = (const float*)d_in[1];
  const float* c0     = (const float*)d_in[2];
  const float* emb    = (const float*)d_in[3];
  const float* Wi     = (const float*)d_in[4];
  const float* Wh     = (const float*)d_in[5];
  const float* bias   = (const float*)d_in[6];
  const float* Wdec   = (const float*)d_in[7];
  const float* bdec   = (const float*)d_in[8];
  float* out = (float*)d_out;

  char* ws = (char*)d_ws;
  unsigned short* x0hi  = (unsigned short*)(ws);                 //  8 MB
  unsigned short* x0lo  = (unsigned short*)(ws + 8388608);       //  8 MB
  unsigned short* x1hi  = (unsigned short*)(ws + 16777216);      //  8 MB
  unsigned short* x1lo  = (unsigned short*)(ws + 25165824);      //  8 MB
  unsigned short* Withi = (unsigned short*)(ws + 33554432);      //  8 MB
  unsigned short* Witlo = (unsigned short*)(ws + 41943040);      //  8 MB
  unsigned short* Whthi = (unsigned short*)(ws + 50331648);      //  8 MB
  unsigned short* Whtlo = (unsigned short*)(ws + 58720256);      //  8 MB
  float*          xg0   = (float*)         (ws + 67108864);      // 64 MB
  unsigned short* hb    = (unsigned short*)(ws + 134217728);     // 512 KB
  float*          h_f32 = (float*)         (ws + 134742016);     // 256 KB
  float*          c_f32 = (float*)         (ws + 135004160);     // 256 KB -> end ~129 MB

  prep_w<<<4096, dim3(32, 8), 0, stream>>>(Wi, Wh, Withi, Witlo, Whthi, Whtlo);
  prep_embed<<<4096, 256, 0, stream>>>(tokens, emb, x0hi, x0lo);
  xg_kernel<<<1024, 256, 0, stream>>>(x0hi, x0lo, Withi, Witlo, bias, xg0);
  prep_state2<<<256, 256, 0, stream>>>(h0, c0, h_f32, c_f32, hb);

  for (int p = 0; p <= T_SZ; ++p) {
    lstm_step2<<<256, 256, 0, stream>>>(hb, x1hi, x1lo, x0hi, x0lo,
                                        Withi, Witlo, Whthi, Whtlo,
                                        xg0, bias, h_f32, c_f32, p);
  }
  save_states2<<<256, 256, 0, stream>>>(h_f32, c_f32, out);

  dec_kernel<<<12576, 256, 0, stream>>>(x0hi, x0lo, Wdec, bdec, out);
}